// Round 6
// baseline (119.880 us; speedup 1.0000x reference)
//
#include <hip/hip_runtime.h>

// conv1d: out[b,i] = sum_{k<16,d<512} x[b,i+k,d] * w[k,d] + bias, zero-pad at end.
// R5: R4's register sliding ring + (1) explicit 2-group register prefetch
// (loads always ~2 groups = ~1100 cy ahead of use), (2) rolled 4-group main
// body (fits L1I; ring slot (32j+f-k)&31 is j-independent), (3) single launch
// with block-uniform tail guards, (4) XCD-contiguous block swizzle.
// Lane owns 2 d's (float2); w=32 VGPR, acc ring=32, prefetch=32.

namespace {
constexpr int S = 4096;
constexpr int D = 512;
constexpr int K = 16;
constexpr int B = 32;
constexpr int SEG = 128;       // outputs per block
constexpr int NCH = SEG / 8;   // 16 chunks of 8 outputs
constexpr int SPR = S / SEG;   // 32 segments per row
constexpr int NBLK = B * SPR;  // 1024 blocks

// FMA one prefetched frame XV into ring slots ((FI - k) & 31); FI,KLO,KHI compile-time
#define FRAME_R(XV, FI, KLO, KHI)              \
  do {                                         \
    _Pragma("unroll")                          \
    for (int k = (KLO); k <= (KHI); ++k) {     \
      const int sl = ((FI) - k) & 31;          \
      acc[sl] = fmaf((XV).x, w[k].x, acc[sl]); \
      acc[sl] = fmaf((XV).y, w[k].y, acc[sl]); \
    }                                          \
  } while (0)

// issue 8 float2 loads of frame-group G into named prefetch regs DST[0..7]
#define PF_GROUP(DST, G)                                      \
  do {                                                        \
    const float* _pp = px + (size_t)(G) * (8 * D);            \
    _Pragma("unroll")                                         \
    for (int f = 0; f < 8; ++f)                               \
      DST[f] = *reinterpret_cast<const float2*>(_pp + f * D); \
  } while (0)

// fold 8 completed ring slots (SB..SB+7, SB compile-time) -> 64-lane sums;
// lane l<8 stores red[C][wv][perm(l)]  (verbatim from R4 -- validated)
#define FOLD(SB, C)                                                           \
  do {                                                                        \
    float v[8];                                                               \
    _Pragma("unroll")                                                         \
    for (int i = 0; i < 8; ++i) {                                             \
      const int sl = ((SB) + i) & 31;                                         \
      v[i] = acc[sl];                                                         \
      acc[sl] = 0.f;                                                          \
    }                                                                         \
    const bool f0 = lane & 1, f1 = lane & 2, f2 = lane & 4;                   \
    _Pragma("unroll")                                                         \
    for (int j = 0; j < 4; ++j) {                                             \
      const float sv = f0 ? v[j] : v[j + 4];                                  \
      const float rv = __shfl_xor(sv, 1, 64);                                 \
      v[j] = (f0 ? v[j + 4] : v[j]) + rv;                                     \
    }                                                                         \
    _Pragma("unroll")                                                         \
    for (int j = 0; j < 2; ++j) {                                             \
      const float sv = f1 ? v[j] : v[j + 2];                                  \
      const float rv = __shfl_xor(sv, 2, 64);                                 \
      v[j] = (f1 ? v[j + 2] : v[j]) + rv;                                     \
    }                                                                         \
    {                                                                         \
      const float sv = f2 ? v[0] : v[1];                                      \
      const float rv = __shfl_xor(sv, 4, 64);                                 \
      float tt = (f2 ? v[1] : v[0]) + rv;                                     \
      tt += __shfl_xor(tt, 8, 64);                                            \
      tt += __shfl_xor(tt, 16, 64);                                           \
      tt += __shfl_xor(tt, 32, 64);                                           \
      if (lane < 8)                                                           \
        red[(C)][wv]                                                          \
           [4 * (lane & 1) + 2 * ((lane >> 1) & 1) + ((lane >> 2) & 1)] = tt; \
    }                                                                         \
  } while (0)

__global__ void conv1d_kernel(const float* __restrict__ x,
                              const float* __restrict__ filt,
                              const float* __restrict__ bias,
                              float* __restrict__ out) {
  __shared__ float red[NCH][4][8];  // 2 KB
  const int tid = threadIdx.x;
  const int lane = tid & 63;
  const int wv = tid >> 6;
  const int d0 = wv * 128 + lane * 2;

  // XCD-contiguous swizzle (NBLK % 8 == 0)
  const int bid = blockIdx.x;
  const int lbid = (bid & 7) * (NBLK / 8) + (bid >> 3);
  const int b = lbid >> 5;        // / SPR
  const int seg = lbid & 31;
  const int seg_start = seg * SEG;
  const bool tail = (seg == SPR - 1);  // epilogue frames are zero padding

  float2 w[K];  // 32 VGPR
#pragma unroll
  for (int k = 0; k < K; ++k)
    w[k] = *reinterpret_cast<const float2*>(filt + k * D + d0);

  float acc[32];
#pragma unroll
  for (int i = 0; i < 32; ++i) acc[i] = 0.f;

  const float* px = x + ((size_t)b * S + seg_start) * D + d0;

  float2 pfA[8], pfB[8];  // 2-group prefetch (compile-time indexed only)
  PF_GROUP(pfA, 0);
  PF_GROUP(pfB, 1);

  // ---- peeled j=0: groups 0..3 (first 15 frames have clamped tap windows) ----
#pragma unroll
  for (int f = 0; f < 8; ++f) FRAME_R(pfA[f], f, 0, f);
  PF_GROUP(pfA, 2);
#pragma unroll
  for (int f = 0; f < 8; ++f) FRAME_R(pfB[f], 8 + f, 0, ((8 + f) < 15 ? (8 + f) : 15));
  PF_GROUP(pfB, 3);
#pragma unroll
  for (int f = 0; f < 8; ++f) FRAME_R(pfA[f], 16 + f, 0, 15);
  FOLD(0, 0);
  PF_GROUP(pfA, 4);
#pragma unroll
  for (int f = 0; f < 8; ++f) FRAME_R(pfB[f], 24 + f, 0, 15);
  FOLD(8, 1);
  PF_GROUP(pfB, 5);

  // ---- rolled main: j=1..3, groups 4j..4j+3 (frames 32j..32j+31) ----
  for (int j = 1; j <= 3; ++j) {
    // i=0: consume pfA = group 4j; fold chunk 4j-2 (slots 16..23); pf 4j+2
#pragma unroll
    for (int f = 0; f < 8; ++f) FRAME_R(pfA[f], f, 0, 15);
    FOLD(16, 4 * j - 2);
    PF_GROUP(pfA, 4 * j + 2);
    // i=1: consume pfB = group 4j+1; fold chunk 4j-1 (slots 24..31); pf 4j+3
#pragma unroll
    for (int f = 0; f < 8; ++f) FRAME_R(pfB[f], 8 + f, 0, 15);
    FOLD(24, 4 * j - 1);
    PF_GROUP(pfB, 4 * j + 3);
    // i=2: consume pfA = group 4j+2; fold chunk 4j (slots 0..7); pf 4j+4
#pragma unroll
    for (int f = 0; f < 8; ++f) FRAME_R(pfA[f], 16 + f, 0, 15);
    FOLD(0, 4 * j);
    if (!tail || j < 3) PF_GROUP(pfA, 4 * j + 4);  // group 16 OOB only for tail
    // i=3: consume pfB = group 4j+3; fold chunk 4j+1 (slots 8..15); pf 4j+5
#pragma unroll
    for (int f = 0; f < 8; ++f) FRAME_R(pfB[f], 24 + f, 0, 15);
    FOLD(8, 4 * j + 1);
    if (!tail || j < 3) PF_GROUP(pfB, 4 * j + 5);  // group 17 OOB only for tail
  }

  // ---- epilogue: halo frames 128..142 (pfA=group 16, pfB=group 17),
  //      skipped for tail blocks (reference zero padding) ----
  if (!tail) {
#pragma unroll
    for (int t = 0; t < 8; ++t) FRAME_R(pfA[t], t, t + 1, 15);
  }
  FOLD(16, 14);
  if (!tail) {
#pragma unroll
    for (int t = 8; t < 15; ++t) FRAME_R(pfB[t - 8], t, t + 1, 15);
  }
  FOLD(24, 15);

  __syncthreads();

  // combine 4 wave-quarters + bias; one coalesced 512 B store per block
  if (tid < SEG) {
    const int c = tid >> 3, o = tid & 7;
    const float v =
        red[c][0][o] + red[c][1][o] + red[c][2][o] + red[c][3][o] + bias[0];
    out[(size_t)b * S + seg_start + tid] = v;
  }
}
}  // namespace

extern "C" void kernel_launch(void* const* d_in, const int* in_sizes, int n_in,
                              void* d_out, int out_size, void* d_ws, size_t ws_size,
                              hipStream_t stream) {
  const float* x = (const float*)d_in[0];
  const float* filt = (const float*)d_in[1];
  const float* bias = (const float*)d_in[2];
  float* out = (float*)d_out;

  hipLaunchKernelGGL(conv1d_kernel, dim3(NBLK), dim3(256), 0, stream,
                     x, filt, bias, out);
}